// Round 1
// baseline (208.906 us; speedup 1.0000x reference)
//
#include <hip/hip_runtime.h>
#include <math.h>

#define B 128
#define T 2048
#define H 200
#define G4 800   // 4*H
#define KP 224   // K padded to multiple of 32
#define ESTR (64 * KP)   // shorts per enc LDS buffer
#define NTILE 8

typedef short short8 __attribute__((ext_vector_type(8)));
typedef float floatx4 __attribute__((ext_vector_type(4)));

__device__ __forceinline__ unsigned short f2bf(float x) {
    unsigned u = __float_as_uint(x);
    return (unsigned short)((u + 0x7fffu + ((u >> 16) & 1u)) >> 16);
}
// pack two floats -> two bf16 (round-nearest-away) in 3 VALU ops
__device__ __forceinline__ unsigned pk2(float a, float b) {
    return __builtin_amdgcn_perm(__float_as_uint(b) + 0x8000u,
                                 __float_as_uint(a) + 0x8000u, 0x07060302u);
}
// tanh(x) = 1 - 2/(exp(2x)+1), hw exp2 + rcp (~1e-6 rel err)
__device__ __forceinline__ float ftanh(float x) {
    float e = __builtin_amdgcn_exp2f(x * 2.885390081777927f);
    float r = __builtin_amdgcn_rcpf(e + 1.f);
    return fmaf(-2.f, r, 1.f);
}
__device__ __forceinline__ float sigm(float x) { return 1.f / (1.f + expf(-x)); }

// ---------------- prep_all ----------------
// blocks 0..255    : Uab row (bf16, zero-padded [256][224])
// blocks 256..455  : W_ihT[k][j] = W_ih[j][1+k]
// blocks 456..655  : W_hhT[k][j] = W_hh[j][k]
// block  656       : wx[j] = W_ih[j][0]
// blocks 657..784  : qb[b][h] = h0[b] @ Wa.T + ba + bua   (float4 dot)
// blocks 785..984  : W1T[k][j] = W1[j][k]   (k<200, j<100)
// blocks 985..1084 : W2T[k][j] = W2[j][k]   (k<100, j<50)
__global__ __launch_bounds__(256) void prep_all(const float* __restrict__ Ua,
                                                const float* __restrict__ Wa,
                                                const float* __restrict__ ba,
                                                const float* __restrict__ bua,
                                                const float* __restrict__ h0,
                                                const float* __restrict__ W_ih,
                                                const float* __restrict__ W_hh,
                                                const float* __restrict__ W1,
                                                const float* __restrict__ W2,
                                                unsigned short* __restrict__ Uab,
                                                float* __restrict__ WihT,
                                                float* __restrict__ WhhT,
                                                float* __restrict__ wx,
                                                float* __restrict__ qb,
                                                float* __restrict__ W1T,
                                                float* __restrict__ W2T) {
    __shared__ __align__(16) float qs[H];
    int bx = blockIdx.x, tid = threadIdx.x;
    if (bx < 256) {
        if (tid < KP) {
            float v = (bx < H && tid < H) ? Ua[bx * H + tid] : 0.f;
            Uab[bx * KP + tid] = f2bf(v);
        }
    } else if (bx < 456) {
        int k = bx - 256;
        for (int j = tid; j < G4; j += 256) WihT[k * G4 + j] = W_ih[(size_t)j * (H + 1) + 1 + k];
    } else if (bx < 656) {
        int k = bx - 456;
        for (int j = tid; j < G4; j += 256) WhhT[k * G4 + j] = W_hh[(size_t)j * H + k];
    } else if (bx == 656) {
        for (int j = tid; j < G4; j += 256) wx[j] = W_ih[(size_t)j * (H + 1)];
    } else if (bx < 785) {
        int b = bx - 657;
        if (tid < H) qs[tid] = h0[b * H + tid];
        __syncthreads();
        if (tid < H) {
            float a = ba[tid] + bua[tid];
            const float4* w  = (const float4*)(Wa + tid * H);
            const float4* qv = (const float4*)qs;
            #pragma unroll 8
            for (int k = 0; k < 50; k++) {
                float4 wv = w[k], q4 = qv[k];
                a = fmaf(wv.x, q4.x, a);
                a = fmaf(wv.y, q4.y, a);
                a = fmaf(wv.z, q4.z, a);
                a = fmaf(wv.w, q4.w, a);
            }
            qb[b * H + tid] = a;
        }
    } else if (bx < 985) {
        int k = bx - 785;
        if (tid < 100) W1T[k * 100 + tid] = W1[tid * H + k];
    } else {
        int k = bx - 985;
        if (tid < 50) W2T[k * 50 + tid] = W2[tid * 100 + k];
    }
}

// ---------------- scores + bounded-softmax + context (pipelined) ----------------
// Grid: 512 = (b, quarter-of-T). Each block: 8 tiles of 64 t, double-buffered LDS,
// register-staged prefetch (T14): issue tile t+1 global loads before computing tile t,
// convert+ds_write after. A-frags + va/qb operands persist in VGPRs for whole block.
// Waves own m-tiles {0-3},{4-6},{7-9},{10-12} (13x16=208 rows cover H=200; zero-rows skipped).

template<int NM>
__device__ __forceinline__ void load_af(short8 af[4][7], const unsigned short* __restrict__ Uab,
                                        int mbase, int r, int q) {
    #pragma unroll
    for (int m = 0; m < NM; m++)
        #pragma unroll
        for (int ks = 0; ks < 7; ks++)
            af[m][ks] = *(const short8*)(Uab + ((mbase + m) * 16 + r) * KP + ks * 32 + q * 8);
}

template<int NM>
__device__ __forceinline__ void load_vq(float va_r[4][4], float qb_r[4][4],
                                        const float* s_va, const float* s_qb, int mbase, int q) {
    #pragma unroll
    for (int m = 0; m < NM; m++)
        #pragma unroll
        for (int g = 0; g < 4; g++) {
            int h = (mbase + m) * 16 + q * 4 + g;
            va_r[m][g] = s_va[h];
            qb_r[m][g] = s_qb[h];
        }
}

template<int NM>
__device__ __forceinline__ void score_tile(const unsigned short* eb, const short8 af[4][7],
                                           const float va_r[4][4], const float qb_r[4][4],
                                           int r, int q, float p[4]) {
    #pragma unroll
    for (int nt = 0; nt < 4; nt++) {
        floatx4 C[NM];
        #pragma unroll
        for (int m = 0; m < NM; m++) C[m] = (floatx4){0.f, 0.f, 0.f, 0.f};
        #pragma unroll
        for (int ks = 0; ks < 7; ks++) {
            short8 bf = *(const short8*)(eb + (nt * 16 + r) * KP + ks * 32 + q * 8);
            #pragma unroll
            for (int m = 0; m < NM; m++)
                C[m] = __builtin_amdgcn_mfma_f32_16x16x32_bf16(af[m][ks], bf, C[m], 0, 0, 0);
        }
        float pp = 0.f;
        #pragma unroll
        for (int m = 0; m < NM; m++)
            #pragma unroll
            for (int g = 0; g < 4; g++)
                pp += va_r[m][g] * ftanh(qb_r[m][g] + C[m][g]);
        p[nt] += pp;
    }
}

__device__ __forceinline__ void stage_write(unsigned short* base, const float4* R, int tid) {
    int rr = tid / 50, cc = tid - rr * 50;
    #pragma unroll
    for (int p2 = 0; p2 < 13; p2++) {
        if (p2 < 12 || tid < 128) {
            unsigned* dst = (unsigned*)(base + rr * KP + cc * 4);
            dst[0] = pk2(R[p2].x, R[p2].y);
            dst[1] = pk2(R[p2].z, R[p2].w);
        }
        cc += 6; rr += 5;
        if (cc >= 50) { cc -= 50; rr += 1; }
    }
}

__global__ __launch_bounds__(256, 2) void scores_ctx(const float* __restrict__ enc,
                                                     const unsigned short* __restrict__ Uab,
                                                     const float* __restrict__ qb,
                                                     const float* __restrict__ Va,
                                                     const float* __restrict__ bva,
                                                     float* __restrict__ ctx_raw,
                                                     float* __restrict__ lsum) {
    __shared__ unsigned short elds[2 * ESTR];          // 57344 B (double buffer, [64][224] bf16)
    __shared__ float part[4][64];
    __shared__ float s_qb[256];
    __shared__ float s_va[256];
    __shared__ float wlds[64];
    __shared__ __align__(16) float ctx_part[4][200];

    int bx = blockIdx.x;
    int b = bx >> 2, chunk = bx & 3;
    int tid = threadIdx.x, w = tid >> 6, lane = tid & 63, r = lane & 15, q = lane >> 4;
    int mbase = (w == 0) ? 0 : (1 + 3 * w);   // m-tiles: {0-3},{4-6},{7-9},{10-12}

    s_qb[tid] = (tid < H) ? qb[b * H + tid] : 0.f;
    s_va[tid] = (tid < H) ? Va[tid] : 0.f;
    float bv = bva[0];

    // zero k-pad columns 200..223 of BOTH buffers once (never overwritten by staging)
    for (int i = tid; i < 1536; i += 256) {
        int bb = i / 768, ii = i - bb * 768;
        int rr = ii / 12, cc = ii - rr * 12;
        *(unsigned*)(elds + bb * ESTR + rr * KP + 200 + 2 * cc) = 0u;
    }

    const float4* src = (const float4*)(enc + ((size_t)b * T + chunk * 512) * H);
    float4 R[13];
    #pragma unroll
    for (int p2 = 0; p2 < 12; p2++) R[p2] = src[tid + p2 * 256];
    if (tid < 128) R[12] = src[tid + 3072];

    short8 af[4][7];   // A-frags persist for whole block
    if (w == 0) load_af<4>(af, Uab, 0, r, q);
    else        load_af<3>(af, Uab, mbase, r, q);

    __syncthreads();   // s_va/s_qb ready

    float va_r[4][4], qb_r[4][4];   // operand preload -> kills per-tile LDS scalar storm
    if (w == 0) load_vq<4>(va_r, qb_r, s_va, s_qb, 0, q);
    else        load_vq<3>(va_r, qb_r, s_va, s_qb, mbase, q);

    float bound = 0.f;   // score bound = sum|Va| + |bva| (register, wave0)
    if (tid < 64) {
        float a = fabsf(s_va[tid]) + fabsf(s_va[tid + 64]) +
                  fabsf(s_va[tid + 128]) + fabsf(s_va[tid + 192]);
        #pragma unroll
        for (int d = 1; d < 64; d <<= 1) a += __shfl_xor(a, d);
        bound = a + fabsf(bv);
    }

    stage_write(elds, R, tid);   // tile 0 -> buf0
    __syncthreads();

    float cacc0 = 0.f, cacc1 = 0.f, cacc2 = 0.f, cacc3 = 0.f;   // ctx accum (4 h per lane)
    float lacc = 0.f;

    for (int tile = 0; tile < NTILE; tile++) {
        const unsigned short* eb = elds + (tile & 1) * ESTR;

        // A: issue next tile's global loads early (latency hides under compute)
        if (tile < NTILE - 1) {
            const float4* s2 = src + (tile + 1) * 3200;
            #pragma unroll
            for (int p2 = 0; p2 < 12; p2++) R[p2] = s2[tid + p2 * 256];
            if (tid < 128) R[12] = s2[tid + 3072];
        }

        // B: scores (MFMA + tanh), all operands in registers
        float p[4] = {0.f, 0.f, 0.f, 0.f};
        __builtin_amdgcn_s_setprio(1);
        if (w == 0) score_tile<4>(eb, af, va_r, qb_r, r, q, p);
        else        score_tile<3>(eb, af, va_r, qb_r, r, q, p);
        __builtin_amdgcn_s_setprio(0);

        // C: cross-q reduce -> per-tile scores -> bounded-softmax weights
        #pragma unroll
        for (int nt = 0; nt < 4; nt++) {
            float pp = p[nt];
            pp += __shfl_xor(pp, 16);
            pp += __shfl_xor(pp, 32);
            if (q == 0) part[w][nt * 16 + r] = pp;
        }
        __syncthreads();
        if (tid < 64) {
            float s = part[0][tid] + part[1][tid] + part[2][tid] + part[3][tid] + bv;
            float we = __builtin_amdgcn_exp2f((s - bound) * 1.4426950408889634f);
            wlds[tid] = we;
            #pragma unroll
            for (int d = 1; d < 64; d <<= 1) we += __shfl_xor(we, d);
            lacc += we;
        }
        __syncthreads();

        // D: ctx accumulate (wave w owns t-range [16w,16w+16), lane<50 owns h=4*lane..+3)
        if (lane < 50) {
            const unsigned short* ebw = eb + (w * 16) * KP + lane * 4;
            #pragma unroll
            for (int j = 0; j < 16; j++) {
                float wt = wlds[w * 16 + j];
                uint2 v = *(const uint2*)(ebw + j * KP);
                cacc0 = fmaf(wt, __uint_as_float(v.x << 16),          cacc0);
                cacc1 = fmaf(wt, __uint_as_float(v.x & 0xffff0000u),  cacc1);
                cacc2 = fmaf(wt, __uint_as_float(v.y << 16),          cacc2);
                cacc3 = fmaf(wt, __uint_as_float(v.y & 0xffff0000u),  cacc3);
            }
        }

        // E: drain prefetch (implicit vmcnt) and write tile t+1 into the other buffer
        if (tile < NTILE - 1) stage_write(elds + ((tile & 1) ^ 1) * ESTR, R, tid);
        __syncthreads();
    }

    // epilogue: combine per-wave ctx partials; ONE atomic per block
    if (lane < 50) {
        float4 cv; cv.x = cacc0; cv.y = cacc1; cv.z = cacc2; cv.w = cacc3;
        *(float4*)&ctx_part[w][lane * 4] = cv;
    }
    __syncthreads();
    if (tid < H)
        atomicAdd(&ctx_raw[b * H + tid],
                  ctx_part[0][tid] + ctx_part[1][tid] + ctx_part[2][tid] + ctx_part[3][tid]);
    if (tid == 0) atomicAdd(&lsum[b], lacc);
}

// ---------------- decoder (fused gc prologue + 5 steps), 512 threads ----------------
__global__ __launch_bounds__(512) void decoder2(const float* __restrict__ x,
                                                const float* __restrict__ c0,
                                                const float* __restrict__ ctx_raw,
                                                const float* __restrict__ lsum,
                                                const float* __restrict__ h0,
                                                const float* __restrict__ WihT,
                                                const float* __restrict__ WhhT,
                                                const float* __restrict__ b_ih,
                                                const float* __restrict__ b_hh,
                                                const float* __restrict__ wx,
                                                const float* __restrict__ W1T,
                                                const float* __restrict__ b1,
                                                const float* __restrict__ W2T,
                                                const float* __restrict__ b2,
                                                const float* __restrict__ W3,
                                                const float* __restrict__ b3,
                                                float* __restrict__ out) {
    __shared__ float s_gc[G4];
    __shared__ float s_wx[G4];
    __shared__ float s_ctx[H];
    __shared__ float s_q[H];
    __shared__ float s_out[H];
    __shared__ float s_o1[100];
    __shared__ float s_o2[50];
    __shared__ float s_w3[64];
    __shared__ float s_x;
    int b = blockIdx.x, tid = threadIdx.x;

    if (tid < H) {
        float invl = 1.f / lsum[b];
        s_ctx[tid] = ctx_raw[b * H + tid] * invl;
        s_q[tid]   = h0[b * H + tid];
    }
    s_wx[tid] = wx[tid];
    if (tid < G4 - 512) s_wx[512 + tid] = wx[512 + tid];
    if (tid < 64) s_w3[tid] = (tid < 50) ? W3[tid] : 0.f;
    if (tid == 0) s_x = x[b];
    float b3v = b3[0];
    __syncthreads();

    // gc[j] = b_ih+b_hh + ctx.Wih[:,1:] + q.Whh   (two j per thread, 4 loads/k in flight)
    {
        int j0 = tid;
        int j1 = 512 + ((tid < 288) ? tid : 287);
        float a0 = b_ih[j0] + b_hh[j0];
        float a1 = b_ih[j1] + b_hh[j1];
        #pragma unroll 4
        for (int k = 0; k < H; k++) {
            float cv = s_ctx[k], qv = s_q[k];
            a0 = fmaf(cv, WihT[k * G4 + j0], a0);
            a0 = fmaf(qv, WhhT[k * G4 + j0], a0);
            a1 = fmaf(cv, WihT[k * G4 + j1], a1);
            a1 = fmaf(qv, WhhT[k * G4 + j1], a1);
        }
        s_gc[j0] = a0;
        if (tid < 288) s_gc[512 + tid] = a1;
    }
    float cprev = (tid < H) ? c0[b * H + tid] : 0.f;
    __syncthreads();

    for (int s = 0; s < 5; s++) {
        float xv = s_x;
        if (tid < H) {
            float ig = s_gc[tid]         + xv * s_wx[tid];
            float fg = s_gc[H + tid]     + xv * s_wx[H + tid];
            float gg = s_gc[2 * H + tid] + xv * s_wx[2 * H + tid];
            float og = s_gc[3 * H + tid] + xv * s_wx[3 * H + tid];
            float c  = sigm(fg) * cprev + sigm(ig) * tanhf(gg);
            float hn = sigm(og) * tanhf(c);
            s_out[tid] = fmaxf(hn, 0.f);
        }
        __syncthreads();
        if (tid < 400) {   // W1: 4 lanes per output, k split 4x50
            int j = tid >> 2, q4 = tid & 3;
            float a = 0.f;
            const float* wp = W1T + (q4 * 50) * 100 + j;
            const float* op = s_out + q4 * 50;
            #pragma unroll 10
            for (int k = 0; k < 50; k++) a = fmaf(wp[k * 100], op[k], a);
            a += __shfl_xor(a, 1);
            a += __shfl_xor(a, 2);
            if (q4 == 0) s_o1[j] = fmaxf(a + b1[j], 0.f);
        }
        __syncthreads();
        if (tid < 200) {   // W2: 4 lanes per output, k split 4x25
            int j = tid >> 2, q4 = tid & 3;
            float a = 0.f;
            const float* wp = W2T + (q4 * 25) * 50 + j;
            const float* op = s_o1 + q4 * 25;
            #pragma unroll 5
            for (int k = 0; k < 25; k++) a = fmaf(wp[k * 50], op[k], a);
            a += __shfl_xor(a, 1);
            a += __shfl_xor(a, 2);
            if (q4 == 0) s_o2[j] = fmaxf(a + b2[j], 0.f);
        }
        __syncthreads();
        if (tid < 64) {   // W3: wave reduce
            float a = (tid < 50) ? s_w3[tid] * s_o2[tid] : 0.f;
            #pragma unroll
            for (int d = 1; d < 64; d <<= 1) a += __shfl_xor(a, d);
            if (tid == 0) {
                float y = a + b3v;
                out[b * 5 + s] = y;
                s_x = y;
            }
        }
        __syncthreads();
    }
}

// ---------------- launch ----------------
extern "C" void kernel_launch(void* const* d_in, const int* in_sizes, int n_in,
                              void* d_out, int out_size, void* d_ws, size_t ws_size,
                              hipStream_t stream) {
    (void)in_sizes; (void)n_in; (void)out_size; (void)ws_size;
    const float* x    = (const float*)d_in[0];
    const float* h0   = (const float*)d_in[1];
    const float* c0   = (const float*)d_in[2];
    const float* enc  = (const float*)d_in[3];
    const float* Wa   = (const float*)d_in[4];
    const float* ba   = (const float*)d_in[5];
    const float* Ua   = (const float*)d_in[6];
    const float* bua  = (const float*)d_in[7];
    const float* Va   = (const float*)d_in[8];
    const float* bva  = (const float*)d_in[9];
    const float* W_ih = (const float*)d_in[10];
    const float* W_hh = (const float*)d_in[11];
    const float* b_ih = (const float*)d_in[12];
    const float* b_hh = (const float*)d_in[13];
    const float* W1   = (const float*)d_in[14];
    const float* b1   = (const float*)d_in[15];
    const float* W2   = (const float*)d_in[16];
    const float* b2   = (const float*)d_in[17];
    const float* W3   = (const float*)d_in[18];
    const float* b3   = (const float*)d_in[19];
    float* out = (float*)d_out;

    char* ws = (char*)d_ws;
    unsigned short* Uab = (unsigned short*)(ws);   // 114688
    float* WihT    = (float*)(ws + 114688);        // 640000
    float* WhhT    = (float*)(ws + 754688);        // 640000
    float* wx      = (float*)(ws + 1394688);       // 3200
    float* qb      = (float*)(ws + 1397888);       // 102400
    float* W1T     = (float*)(ws + 1500288);       // 80000
    float* W2T     = (float*)(ws + 1580288);       // 20000
    float* ctx_raw = (float*)(ws + 1600288);       // 102400
    float* lsum    = (float*)(ws + 1702688);       // 512

    hipMemsetAsync(ws + 1600288, 0, 102912, stream);   // ctx_raw + lsum
    prep_all<<<dim3(1085), 256, 0, stream>>>(Ua, Wa, ba, bua, h0, W_ih, W_hh, W1, W2,
                                             Uab, WihT, WhhT, wx, qb, W1T, W2T);
    scores_ctx<<<dim3(512), 256, 0, stream>>>(enc, Uab, qb, Va, bva, ctx_raw, lsum);
    decoder2<<<dim3(B), 512, 0, stream>>>(x, c0, ctx_raw, lsum, h0, WihT, WhhT,
                                          b_ih, b_hh, wx, W1T, b1, W2T, b2, W3, b3, out);
}